// Round 4
// baseline (72.424 us; speedup 1.0000x reference)
//
#include <hip/hip_runtime.h>

// SpikeFP32LookupExp2: out[pos, :] = table_bits[j(pos), :] where
// j(pos) = sum_k (idx_bits[pos,k] > 0.5) << k.  Pure row-gather, memory-bound
// (~310 MB irreducible traffic, write-dominated; box ceiling ~7 TB/s per the
// harness fill kernels).
//
// Round 4 tune:
//  - Persistent grid: 2048 blocks = 8 blocks/CU x 256 CU, all 32 waves/CU
//    co-resident (VGPR use is tiny); 32 iterations/thread, no second
//    dispatch round.
//  - unroll 8: 8 independent {idx load -> ballot -> table load -> store}
//    chains in flight per wave.
//  - Nontemporal loads on idx_bits (read-once) + nontemporal stores on out
//    (write-once) keep L2 free for the 4 KB table.
//  - j via ballot: lanes with lane8<5 load one bit each; one coalesced dword
//    load per wave covers 8 positions.

typedef float floatx4 __attribute__((ext_vector_type(4)));

__global__ __launch_bounds__(256) void spike_lookup_kernel(
    const float* __restrict__ idx_bits,   // [n_pos * 5]
    const float* __restrict__ table_bits, // [32 * 32]
    float* __restrict__ out,              // [n_pos * 32]
    long n_pos) {
  const long total4 = n_pos * 8;  // total float4 outputs
  const long nthreads = (long)gridDim.x * blockDim.x;
  const long gid = (long)blockIdx.x * blockDim.x + threadIdx.x;
  const int lane8 = (int)(gid & 7);        // which float4 of the row
  const unsigned shift = threadIdx.x & 56; // group base within the wave

#pragma unroll 8
  for (long g = gid; g < total4; g += nthreads) {
    const long pos = g >> 3;
    float v = 0.0f;
    if (lane8 < 5) v = __builtin_nontemporal_load(idx_bits + pos * 5 + lane8);
    const unsigned long long m = __ballot(v > 0.5f);
    const unsigned j = (unsigned)((m >> shift) & 31ull);

    const floatx4 row = *reinterpret_cast<const floatx4*>(
        table_bits + (j << 5) + (lane8 << 2));     // 4 KB table, L1-resident

    __builtin_nontemporal_store(row,
                                reinterpret_cast<floatx4*>(out + (g << 2)));
  }
}

extern "C" void kernel_launch(void* const* d_in, const int* in_sizes, int n_in,
                              void* d_out, int out_size, void* d_ws, size_t ws_size,
                              hipStream_t stream) {
  const float* idx_bits = (const float*)d_in[0];    // (1024, 2048, 5) f32
  const float* table_bits = (const float*)d_in[1];  // (32, 32) f32
  float* out = (float*)d_out;                       // (1024, 2048, 32) f32

  const long n_pos = in_sizes[0] / 5;  // 2,097,152
  const int block = 256;
  const int grid = 2048;  // 8 blocks/CU x 256 CU, fully resident; 32 iters/thread

  spike_lookup_kernel<<<grid, block, 0, stream>>>(idx_bits, table_bits, out,
                                                  n_pos);
}

// Round 5
// 52.106 us; speedup vs baseline: 1.3899x; 1.3899x over previous
//
#include <hip/hip_runtime.h>

// SpikeFP32LookupExp2: out[pos, :] = table_bits[j(pos), :] where
// j(pos) = sum_k (idx_bits[pos,k] > 0.5) << k.  Pure row-gather, memory-bound
// (~310 MB irreducible traffic, write-dominated; box ceiling ~7 TB/s per the
// harness fill kernels -> ~44 us floor).
//
// Round 5 = round 3 (51.6 us, proven) + branchless idx load:
//  - 8 lanes per position; each lane stores one float4 of the 128 B row
//    (fully coalesced, 1 KB per wave store instruction).
//  - Branchless j via ballot: every lane loads idx_bits[pos*5 + min(lane8,4)]
//    (lanes 5-7 redundantly re-read bit 4 from the same cache line; their
//    ballot bits sit at group bits 5-7 and are discarded by the &31).
//    No divergent branch -> the unrolled iterations' loads cluster early.
//  - Grid-stride, 16 iterations/thread, unroll 4: 4 independent
//    load->ballot->gather->store chains in flight per wave.
//  - Nontemporal stores (write-once stream, keep L2 for idx + table).
//    NO nontemporal load: the builtin blocked if-conversion in R4 and
//    re-serialized the chains (72 us).

typedef float floatx4 __attribute__((ext_vector_type(4)));

__global__ __launch_bounds__(256) void spike_lookup_kernel(
    const float* __restrict__ idx_bits,   // [n_pos * 5]
    const float* __restrict__ table_bits, // [32 * 32]
    float* __restrict__ out,              // [n_pos * 32]
    long n_pos) {
  const long total4 = n_pos * 8;  // total float4 outputs
  const long nthreads = (long)gridDim.x * blockDim.x;
  const long gid = (long)blockIdx.x * blockDim.x + threadIdx.x;
  const int lane8 = (int)(gid & 7);              // which float4 of the row
  const int bit_lane = lane8 < 5 ? lane8 : 4;    // clamped: branchless load
  const unsigned shift = threadIdx.x & 56;       // group base within the wave

#pragma unroll 4
  for (long g = gid; g < total4; g += nthreads) {
    const long pos = g >> 3;
    const float v = idx_bits[pos * 5 + bit_lane];  // unconditional, coalesced
    const unsigned long long m = __ballot(v > 0.5f);
    const unsigned j = (unsigned)((m >> shift) & 31ull);  // bits 5-7 masked

    const floatx4 row = *reinterpret_cast<const floatx4*>(
        table_bits + (j << 5) + (lane8 << 2));     // 4 KB table, L1-resident

    __builtin_nontemporal_store(row,
                                reinterpret_cast<floatx4*>(out + (g << 2)));
  }
}

extern "C" void kernel_launch(void* const* d_in, const int* in_sizes, int n_in,
                              void* d_out, int out_size, void* d_ws, size_t ws_size,
                              hipStream_t stream) {
  const float* idx_bits = (const float*)d_in[0];    // (1024, 2048, 5) f32
  const float* table_bits = (const float*)d_in[1];  // (32, 32) f32
  float* out = (float*)d_out;                       // (1024, 2048, 32) f32

  const long n_pos = in_sizes[0] / 5;  // 2,097,152
  const int block = 256;
  const int grid = 4096;  // proven best (R3); 16 float4s per thread

  spike_lookup_kernel<<<grid, block, 0, stream>>>(idx_bits, table_bits, out,
                                                  n_pos);
}

// Round 6
// 51.841 us; speedup vs baseline: 1.3970x; 1.0051x over previous
//
#include <hip/hip_runtime.h>

// SpikeFP32LookupExp2: out[pos, :] = table_bits[j(pos), :] where
// j(pos) = sum_k (idx_bits[pos,k] > 0.5) << k.  Pure row-gather, memory-bound
// (~310 MB irreducible traffic, 87% write; measured ceilings: copy 6.29 TB/s,
// pure-write fill 7.0 TB/s -> floor 45-49 us).
//
// Round 6 = round 5 with ONE change: unroll 4 -> 8 (isolated this time; R4
// changed grid+unroll+nt-load together and the nt-load's divergence was the
// regression).  8 independent load->ballot->gather->store chains per wave.
//  - 8 lanes per position, one float4 store each: 1 KB coalesced wave stores.
//  - Branchless ballot-j: every lane loads idx_bits[pos*5 + min(lane8,4)];
//    ballot bits 5-7 of each group are discarded by &31.
//  - Nontemporal stores (write-once stream).

typedef float floatx4 __attribute__((ext_vector_type(4)));

__global__ __launch_bounds__(256) void spike_lookup_kernel(
    const float* __restrict__ idx_bits,   // [n_pos * 5]
    const float* __restrict__ table_bits, // [32 * 32]
    float* __restrict__ out,              // [n_pos * 32]
    long n_pos) {
  const long total4 = n_pos * 8;  // total float4 outputs
  const long nthreads = (long)gridDim.x * blockDim.x;
  const long gid = (long)blockIdx.x * blockDim.x + threadIdx.x;
  const int lane8 = (int)(gid & 7);              // which float4 of the row
  const int bit_lane = lane8 < 5 ? lane8 : 4;    // clamped: branchless load
  const unsigned shift = threadIdx.x & 56;       // group base within the wave

#pragma unroll 8
  for (long g = gid; g < total4; g += nthreads) {
    const long pos = g >> 3;
    const float v = idx_bits[pos * 5 + bit_lane];  // unconditional, coalesced
    const unsigned long long m = __ballot(v > 0.5f);
    const unsigned j = (unsigned)((m >> shift) & 31ull);  // bits 5-7 masked

    const floatx4 row = *reinterpret_cast<const floatx4*>(
        table_bits + (j << 5) + (lane8 << 2));     // 4 KB table, L1-resident

    __builtin_nontemporal_store(row,
                                reinterpret_cast<floatx4*>(out + (g << 2)));
  }
}

extern "C" void kernel_launch(void* const* d_in, const int* in_sizes, int n_in,
                              void* d_out, int out_size, void* d_ws, size_t ws_size,
                              hipStream_t stream) {
  const float* idx_bits = (const float*)d_in[0];    // (1024, 2048, 5) f32
  const float* table_bits = (const float*)d_in[1];  // (32, 32) f32
  float* out = (float*)d_out;                       // (1024, 2048, 32) f32

  const long n_pos = in_sizes[0] / 5;  // 2,097,152
  const int block = 256;
  const int grid = 4096;  // proven best (R3/R5); 16 float4s per thread

  spike_lookup_kernel<<<grid, block, 0, stream>>>(idx_bits, table_bits, out,
                                                  n_pos);
}